// Round 29
// baseline (83.825 us; speedup 1.0000x reference)
//
#include <hip/hip_runtime.h>
#include <math.h>

// ManifoldHyperConnectionFuse on MI355X — R28: T14 async-STAGE across tiles.
// R27 (unroll) null: compiler won't cross-iteration pipeline (VGPR 60).
// Remaining serialization: stage->compute per block-tile. R28: each block
// processes 2 tiles (NTOK=8, grid 2048); tile t+1's global loads are issued
// in two 4-load chunks interleaved with tile t's e-halves, pack+ds_write
// after the covered compute (T14 issue-early/write-late). Double-buffered
// LDS tiles (2x16KB). T=2/wave (R25: T=2 == T=4 at b128). Regs ~74 <= 84.

typedef __attribute__((ext_vector_type(2))) _Float16 h2v;

__device__ __forceinline__ float fdot2f(unsigned int a, unsigned int b, float c) {
#if __has_builtin(__builtin_amdgcn_fdot2)
    return __builtin_amdgcn_fdot2(__builtin_bit_cast(h2v, a),
                                  __builtin_bit_cast(h2v, b), c, false);
#else
    h2v av = __builtin_bit_cast(h2v, a);
    h2v bv = __builtin_bit_cast(h2v, b);
    return fmaf((float)av[1], (float)bv[1],
           fmaf((float)av[0], (float)bv[0], c));
#endif
}

__device__ __forceinline__ unsigned int pk_f16(float a, float b) {
    const auto p = __builtin_amdgcn_cvt_pkrtz(a, b);   // __fp16x2
    return __builtin_bit_cast(unsigned int, p);
}

__device__ __forceinline__ float sigmoid_f(float z) {
    return 1.0f / (1.0f + __expf(-z));
}

// sum over each aligned 16-lane row via DPP row_ror (VALU-only)
__device__ __forceinline__ float row16_sum(float x) {
    x += __int_as_float(__builtin_amdgcn_update_dpp(
        0, __float_as_int(x), 0x121, 0xf, 0xf, false)); // row_ror:1
    x += __int_as_float(__builtin_amdgcn_update_dpp(
        0, __float_as_int(x), 0x122, 0xf, 0xf, false)); // row_ror:2
    x += __int_as_float(__builtin_amdgcn_update_dpp(
        0, __float_as_int(x), 0x124, 0xf, 0xf, false)); // row_ror:4
    x += __int_as_float(__builtin_amdgcn_update_dpp(
        0, __float_as_int(x), 0x128, 0xf, 0xf, false)); // row_ror:8
    return x;
}

// ---- prep: fold alpha*nw*w -> f16 wt[24][1024] (n-major) in d_ws ----
__global__ __launch_bounds__(256)
void prep_kernel(const float* __restrict__ nw,
                 const float* __restrict__ w,
                 const float* __restrict__ alpha,
                 unsigned short* __restrict__ wt)
{
    const int tid = blockIdx.x * 256 + threadIdx.x;   // 6144 threads
    const int flat = 4 * tid;                          // w is [k][n], flat=k*24+n
    const float4 w4 = *(const float4*)(w + flat);
    const float a0 = alpha[0], a1 = alpha[1], a2 = alpha[2];
    const float vals[4] = {w4.x, w4.y, w4.z, w4.w};
    #pragma unroll
    for (int c = 0; c < 4; ++c) {
        const int f = flat + c;
        const int k = f / 24;
        const int n = f - 24 * k;
        const float as = (n < 4) ? a0 : ((n < 8) ? a1 : a2);
        const unsigned int p = pk_f16(as * nw[k] * vals[c], 0.f);
        wt[n * 1024 + k] = (unsigned short)(p & 0xffffu);
    }
}

__global__ __launch_bounds__(256, 3)
void mhc_kernel(const float* __restrict__ h,
                const unsigned short* __restrict__ wt,
                const float* __restrict__ beta,
                float* __restrict__ out)
{
    const int tid  = threadIdx.x;
    const int lane = tid & 63;
    const int wv   = tid >> 6;     // wave id: owns tokens {2wv, 2wv+1}
    const int ksl  = lane & 15;    // k-slice lane
    const int ng   = lane >> 4;    // n-group (6 n's each)

    __shared__ unsigned int tileA[8 * 512];  // f16 tile buf 0, 16KB
    __shared__ unsigned int tileB[8 * 512];  // f16 tile buf 1, 16KB
    __shared__ float Hpart[8][28];
    __shared__ float smalls[8][26];

    const long tokbase = (long)blockIdx.x * 16;   // 2 tiles x 8 tokens

    // ---- prologue: stage tile 0 into tileA ----
    {
        const float* src = h + tokbase * 1024 + 4 * tid;
        #pragma unroll
        for (int i = 0; i < 8; ++i) {
            const float4 v = *(const float4*)(src + 1024 * i);
            uint2 u;
            u.x = pk_f16(v.x, v.y);
            u.y = pk_f16(v.z, v.w);
            *(uint2*)(tileA + i * 512 + 2 * tid) = u;
        }
    }
    __syncthreads();

    #pragma unroll
    for (int t = 0; t < 2; ++t) {
        unsigned int* cur = (t == 0) ? tileA : tileB;
        unsigned int* nxt = (t == 0) ? tileB : tileA;
        const bool has_next = (t == 0);
        const long tok0 = tokbase + t * 8;
        const float* src2 = h + (tok0 + 8) * 1024 + 4 * tid;  // next tile src

        // ---- phase A on cur, with T14 async stage of nxt ----
        const int t0 = 2 * wv;
        const uint4* txp = (const uint4*)cur + t0 * 128 + ksl;
        const uint4* twp = (const uint4*)wt + (6 * ng) * 128 + ksl;

        float acc[2][6], r2[2];
        #pragma unroll
        for (int tt = 0; tt < 2; ++tt) {
            r2[tt] = 0.f;
            #pragma unroll
            for (int j = 0; j < 6; ++j) acc[tt][j] = 0.f;
        }

        float4 st0, st1, st2, st3;
        if (has_next) {                       // issue chunk0 loads EARLY
            st0 = *(const float4*)(src2);
            st1 = *(const float4*)(src2 + 1024);
            st2 = *(const float4*)(src2 + 2048);
            st3 = *(const float4*)(src2 + 3072);
        }

        #pragma unroll
        for (int e = 0; e < 4; ++e) {         // e-half 0 (covers chunk0)
            uint4 xw[2];
            #pragma unroll
            for (int tt = 0; tt < 2; ++tt) xw[tt] = txp[tt * 128 + e * 16];
            uint4 wr[6];
            #pragma unroll
            for (int j = 0; j < 6; ++j) wr[j] = twp[j * 128 + e * 16];
            #pragma unroll
            for (int j = 0; j < 6; ++j) {
                #pragma unroll
                for (int tt = 0; tt < 2; ++tt) {
                    float a = acc[tt][j];
                    a = fdot2f(xw[tt].x, wr[j].x, a);
                    a = fdot2f(xw[tt].y, wr[j].y, a);
                    a = fdot2f(xw[tt].z, wr[j].z, a);
                    a = fdot2f(xw[tt].w, wr[j].w, a);
                    acc[tt][j] = a;
                }
            }
            #pragma unroll
            for (int tt = 0; tt < 2; ++tt) {
                float r = r2[tt];
                r = fdot2f(xw[tt].x, xw[tt].x, r);
                r = fdot2f(xw[tt].y, xw[tt].y, r);
                r = fdot2f(xw[tt].z, xw[tt].z, r);
                r = fdot2f(xw[tt].w, xw[tt].w, r);
                r2[tt] = r;
            }
        }

        if (has_next) {                       // write chunk0 LATE (covered)
            uint2 u;
            u.x = pk_f16(st0.x, st0.y); u.y = pk_f16(st0.z, st0.w);
            *(uint2*)(nxt + 0 * 512 + 2 * tid) = u;
            u.x = pk_f16(st1.x, st1.y); u.y = pk_f16(st1.z, st1.w);
            *(uint2*)(nxt + 1 * 512 + 2 * tid) = u;
            u.x = pk_f16(st2.x, st2.y); u.y = pk_f16(st2.z, st2.w);
            *(uint2*)(nxt + 2 * 512 + 2 * tid) = u;
            u.x = pk_f16(st3.x, st3.y); u.y = pk_f16(st3.z, st3.w);
            *(uint2*)(nxt + 3 * 512 + 2 * tid) = u;
            // issue chunk1 loads
            st0 = *(const float4*)(src2 + 4096);
            st1 = *(const float4*)(src2 + 5120);
            st2 = *(const float4*)(src2 + 6144);
            st3 = *(const float4*)(src2 + 7168);
        }

        #pragma unroll
        for (int e = 4; e < 8; ++e) {         // e-half 1 (covers chunk1)
            uint4 xw[2];
            #pragma unroll
            for (int tt = 0; tt < 2; ++tt) xw[tt] = txp[tt * 128 + e * 16];
            uint4 wr[6];
            #pragma unroll
            for (int j = 0; j < 6; ++j) wr[j] = twp[j * 128 + e * 16];
            #pragma unroll
            for (int j = 0; j < 6; ++j) {
                #pragma unroll
                for (int tt = 0; tt < 2; ++tt) {
                    float a = acc[tt][j];
                    a = fdot2f(xw[tt].x, wr[j].x, a);
                    a = fdot2f(xw[tt].y, wr[j].y, a);
                    a = fdot2f(xw[tt].z, wr[j].z, a);
                    a = fdot2f(xw[tt].w, wr[j].w, a);
                    acc[tt][j] = a;
                }
            }
            #pragma unroll
            for (int tt = 0; tt < 2; ++tt) {
                float r = r2[tt];
                r = fdot2f(xw[tt].x, xw[tt].x, r);
                r = fdot2f(xw[tt].y, xw[tt].y, r);
                r = fdot2f(xw[tt].z, xw[tt].z, r);
                r = fdot2f(xw[tt].w, xw[tt].w, r);
                r2[tt] = r;
            }
        }

        if (has_next) {                       // write chunk1 LATE
            uint2 u;
            u.x = pk_f16(st0.x, st0.y); u.y = pk_f16(st0.z, st0.w);
            *(uint2*)(nxt + 4 * 512 + 2 * tid) = u;
            u.x = pk_f16(st1.x, st1.y); u.y = pk_f16(st1.z, st1.w);
            *(uint2*)(nxt + 5 * 512 + 2 * tid) = u;
            u.x = pk_f16(st2.x, st2.y); u.y = pk_f16(st2.z, st2.w);
            *(uint2*)(nxt + 6 * 512 + 2 * tid) = u;
            u.x = pk_f16(st3.x, st3.y); u.y = pk_f16(st3.z, st3.w);
            *(uint2*)(nxt + 7 * 512 + 2 * tid) = u;
        }

        // ---- DPP reduce -> Hpart ----
        #pragma unroll
        for (int tt = 0; tt < 2; ++tt) {
            #pragma unroll
            for (int j = 0; j < 6; ++j) acc[tt][j] = row16_sum(acc[tt][j]);
            r2[tt] = row16_sum(r2[tt]);
        }
        if (ksl == 0) {
            #pragma unroll
            for (int tt = 0; tt < 2; ++tt) {
                #pragma unroll
                for (int j = 0; j < 6; ++j)
                    Hpart[t0 + tt][6 * ng + j] = acc[tt][j];
                if (ng == 0) Hpart[t0 + tt][24] = r2[tt];
            }
        }
        __syncthreads();

        // ---- scalar phase: lanes 0..7, one token each ----
        if (tid < 8) {
            const int tk = tid;
            float Hp[24];
            #pragma unroll
            for (int q = 0; q < 24; ++q) Hp[q] = Hpart[tk][q];
            const float r2v = Hpart[tk][24];
            const float r_ = 1.0f / (sqrtf(r2v) * 0.03125f + 1e-6f);

            float Hpre[4], Hpost[4], K[16];
            #pragma unroll
            for (int n = 0; n < 4; ++n)
                Hpre[n] = sigmoid_f(fmaf(r_, Hp[n], beta[n]));
            #pragma unroll
            for (int n = 0; n < 4; ++n)
                Hpost[n] = 2.0f * sigmoid_f(fmaf(r_, Hp[4 + n], beta[4 + n]));
            #pragma unroll
            for (int q = 0; q < 16; ++q)
                K[q] = __expf(fmaf(r_, Hp[8 + q], beta[8 + q]));

            float u0=1.f,u1=1.f,u2=1.f,u3=1.f;
            float v0=1.f,v1=1.f,v2=1.f,v3=1.f;
            for (int itr = 0; itr < 10; ++itr) {
                u0 = 1.0f/(K[0]*v0  + K[1]*v1  + K[2]*v2  + K[3]*v3  + 1e-8f);
                u1 = 1.0f/(K[4]*v0  + K[5]*v1  + K[6]*v2  + K[7]*v3  + 1e-8f);
                u2 = 1.0f/(K[8]*v0  + K[9]*v1  + K[10]*v2 + K[11]*v3 + 1e-8f);
                u3 = 1.0f/(K[12]*v0 + K[13]*v1 + K[14]*v2 + K[15]*v3 + 1e-8f);
                v0 = 1.0f/(K[0]*u0  + K[4]*u1  + K[8]*u2  + K[12]*u3 + 1e-8f);
                v1 = 1.0f/(K[1]*u0  + K[5]*u1  + K[9]*u2  + K[13]*u3 + 1e-8f);
                v2 = 1.0f/(K[2]*u0  + K[6]*u1  + K[10]*u2 + K[14]*u3 + 1e-8f);
                v3 = 1.0f/(K[3]*u0  + K[7]*u1  + K[11]*u2 + K[15]*u3 + 1e-8f);
            }
            smalls[tk][0] = Hpre[0];  smalls[tk][1] = Hpre[1];
            smalls[tk][2] = Hpre[2];  smalls[tk][3] = Hpre[3];
            smalls[tk][4] = Hpost[0]; smalls[tk][5] = Hpost[1];
            smalls[tk][6] = Hpost[2]; smalls[tk][7] = Hpost[3];
            smalls[tk][8]  = u0*K[0]*v0;   smalls[tk][9]  = u0*K[1]*v1;
            smalls[tk][10] = u0*K[2]*v2;   smalls[tk][11] = u0*K[3]*v3;
            smalls[tk][12] = u1*K[4]*v0;   smalls[tk][13] = u1*K[5]*v1;
            smalls[tk][14] = u1*K[6]*v2;   smalls[tk][15] = u1*K[7]*v3;
            smalls[tk][16] = u2*K[8]*v0;   smalls[tk][17] = u2*K[9]*v1;
            smalls[tk][18] = u2*K[10]*v2;  smalls[tk][19] = u2*K[11]*v3;
            smalls[tk][20] = u3*K[12]*v0;  smalls[tk][21] = u3*K[13]*v1;
            smalls[tk][22] = u3*K[14]*v2;  smalls[tk][23] = u3*K[15]*v3;
        }
        __syncthreads();

        // ---- phase C: x from cur tile ----
        const int gg = wv;
        for (int it = 0; it < 8; ++it) {
            const uint2* tl = (const uint2*)cur + it * 256 + lane;
            float xm[4][4];
            #pragma unroll
            for (int m = 0; m < 4; ++m) {
                const uint2 u = tl[m * 64];
                const h2v p0 = __builtin_bit_cast(h2v, u.x);
                const h2v p1 = __builtin_bit_cast(h2v, u.y);
                xm[m][0] = (float)p0[0]; xm[m][1] = (float)p0[1];
                xm[m][2] = (float)p1[0]; xm[m][3] = (float)p1[1];
            }

            const float hp0 = smalls[it][0], hp1 = smalls[it][1];
            const float hp2 = smalls[it][2], hp3 = smalls[it][3];
            const float hpost = smalls[it][4 + gg];
            const float P0 = smalls[it][8 + 4*gg + 0];
            const float P1 = smalls[it][8 + 4*gg + 1];
            const float P2 = smalls[it][8 + 4*gg + 2];
            const float P3 = smalls[it][8 + 4*gg + 3];

            float4 o;
            #pragma unroll
            for (int c = 0; c < 4; ++c) {
                const float hpre = hp0*xm[0][c] + hp1*xm[1][c]
                                 + hp2*xm[2][c] + hp3*xm[3][c];
                const float res  = P0*xm[0][c] + P1*xm[1][c]
                                 + P2*xm[2][c] + P3*xm[3][c];
                ((float*)&o)[c] = fmaf(hpost, hpre, res);
            }
            *(float4*)(out + (tok0 + it) * 1024 + gg * 256 + 4 * lane) = o;
        }
        __syncthreads();   // cur free for reuse; nxt fully written
    }
}

extern "C" void kernel_launch(void* const* d_in, const int* in_sizes, int n_in,
                              void* d_out, int out_size, void* d_ws, size_t ws_size,
                              hipStream_t stream) {
    const float* h     = (const float*)d_in[0];
    const float* nw    = (const float*)d_in[1];
    const float* w     = (const float*)d_in[2];
    const float* alpha = (const float*)d_in[3];
    const float* beta  = (const float*)d_in[4];
    float* out = (float*)d_out;
    unsigned short* wt = (unsigned short*)d_ws;   // 24*1024*2B = 48KB

    prep_kernel<<<24, 256, 0, stream>>>(nw, w, alpha, wt);
    // 2048 blocks x 2 tiles x 8 tokens = 32768
    mhc_kernel<<<2048, 256, 0, stream>>>(h, wt, beta, out);
}